// Round 5
// baseline (527.519 us; speedup 1.0000x reference)
//
#include <hip/hip_runtime.h>

#define ND 128          // NODE_SIZE
#define ESZ 20          // EDGE_SIZE
#define NN 20000        // N_NODES
#define NE 600000       // N_EDGES
#define PI_F 3.14159265358979323846f
#define CUT 5.0f

using short8 = __attribute__((ext_vector_type(8))) short;   // 8 bf16 (4 VGPR)
using f32x4  = __attribute__((ext_vector_type(4))) float;   // MFMA C/D
using hh2    = __attribute__((ext_vector_type(2))) _Float16;

__device__ __forceinline__ float silu_f(float x) { return x / (1.0f + __expf(-x)); }

__device__ __forceinline__ unsigned short f2bf(float x) {
    unsigned u = __float_as_uint(x);
    unsigned r = (u + 0x7FFFu + ((u >> 16) & 1u)) >> 16;
    return (unsigned short)r;
}
__device__ __forceinline__ float bf2f(unsigned short h) {
    return __uint_as_float(((unsigned)h) << 16);
}
__device__ __forceinline__ unsigned pack2bf(float x, float y) {
    return (unsigned)f2bf(x) | ((unsigned)f2bf(y) << 16);
}
__device__ __forceinline__ unsigned pack2h(float x, float y) {
    _Float16 a = (_Float16)x, b = (_Float16)y;
    unsigned short ua = __builtin_bit_cast(unsigned short, a);
    unsigned short ub = __builtin_bit_cast(unsigned short, b);
    return (unsigned)ua | ((unsigned)ub << 16);
}
__device__ __forceinline__ float dot2u(unsigned a, hh2 b, float acc) {
    return __builtin_amdgcn_fdot2(__builtin_bit_cast(hh2, a), b, acc, false);
}

// ---------------------------------------------------------------------------
// weight pack helper (bf16 B-fragment layout for 16x16x32 MFMA)
// ---------------------------------------------------------------------------
__device__ __forceinline__ void pack_w(const float* __restrict__ W,
                                       unsigned short* __restrict__ P,
                                       int s, int K, int N) {
    int k = s / N, n = s - k * N;
    int dst = ((((n >> 4) * (K >> 5) + (k >> 5)) * 64) +
               (((k >> 3) & 3) << 4) + (n & 15)) * 8 + (k & 7);
    P[dst] = f2bf(W[s]);
}

// ---------------------------------------------------------------------------
// k_front: fused prep (nsb bf16 pack, gnh high halves, weight packs,
// Wf fp16 pack (11 rows), dst histogram). Out-copy DROPPED: k_edge9 writes
// out_s/out_v for every node (ns/nsv + messages) with plain stores.
// ---------------------------------------------------------------------------
#define R0 1920000L
#define R1 (R0 + 180224L)
#define R2 (R1 + 4224L)
#define R3 (R2 + 600000L)

__global__ __launch_bounds__(256) void k_front(
    const float4* __restrict__ ns4, const float4* __restrict__ nsv4,
    const int* __restrict__ eidx,
    const float* __restrict__ Wf, const float* __restrict__ bfb,
    const float* __restrict__ Wm1, const float* __restrict__ Wm2,
    const float* __restrict__ WU, const float* __restrict__ WV,
    const float* __restrict__ Wa1, const float* __restrict__ Wa2,
    ushort4* __restrict__ nsb4, unsigned* __restrict__ gnh,
    unsigned short* __restrict__ p1, unsigned short* __restrict__ p2,
    unsigned short* __restrict__ pU, unsigned short* __restrict__ pV,
    unsigned short* __restrict__ pa1, unsigned short* __restrict__ pa2,
    unsigned* __restrict__ wfh, int* __restrict__ counts) {
    long gid = (long)blockIdx.x * 256 + threadIdx.x;
    if (gid < R0) {
        long i = gid;
        const long S4 = (long)NN * ND / 4;
        if (i < S4) {
            float4 v = ns4[i];
            ushort4 h; h.x = f2bf(v.x); h.y = f2bf(v.y); h.z = f2bf(v.z); h.w = f2bf(v.w);
            nsb4[i] = h;
        }
        float4 w = nsv4[i];
        // nvh -> high halves of gnh
        unsigned short* gs = (unsigned short*)gnh;
        long b = i * 4;
        gs[(b + 0) * 2 + 1] = f2bf(w.x);
        gs[(b + 1) * 2 + 1] = f2bf(w.y);
        gs[(b + 2) * 2 + 1] = f2bf(w.z);
        gs[(b + 3) * 2 + 1] = f2bf(w.w);
    } else if (gid < R1) {
        int i = (int)(gid - R0);
        if      (i <  16384) pack_w(Wm1, p1, i,          128, 128);
        else if (i <  65536) pack_w(Wm2, p2, i - 16384,  128, 384);
        else if (i <  81920) pack_w(WU,  pU, i - 65536,  128, 128);
        else if (i <  98304) pack_w(WV,  pV, i - 81920,  128, 128);
        else if (i < 131072) pack_w(Wa1, pa1, i - 98304, 256, 128);
        else                 pack_w(Wa2, pa2, i - 131072,128, 384);
    } else if (gid < R2) {
        int j = (int)(gid - R1);        // 11*384
        int p = j / 384, cc = j - p * 384;
        float a = 0.f, b = 0.f;
        if (p < 10) { a = Wf[(2 * p) * 384 + cc]; b = Wf[(2 * p + 1) * 384 + cc]; }
        else if (p == 10) { a = bfb[cc]; }
        wfh[p * 384 + cc] = pack2h(a, b);
    } else if (gid < R3) {
        int e = (int)(gid - R2);
        atomicAdd(&counts[eidx[2 * e + 1]], 1);
    }
}

// ---------------------------------------------------------------------------
// CSR scan
// ---------------------------------------------------------------------------
#define SCAN_T 1024
__global__ __launch_bounds__(SCAN_T) void k_scan(const int* __restrict__ counts,
                                                 int* __restrict__ offsets,
                                                 int* __restrict__ cursor) {
    __shared__ int part[SCAN_T];
    const int t = threadIdx.x;
    const int CPT = (NN + SCAN_T - 1) / SCAN_T;
    const int base = t * CPT;
    int sum = 0;
    for (int i = 0; i < CPT; ++i) {
        int idx = base + i;
        if (idx < NN) sum += counts[idx];
    }
    part[t] = sum;
    __syncthreads();
    for (int off = 1; off < SCAN_T; off <<= 1) {
        int v = (t >= off) ? part[t - off] : 0;
        __syncthreads();
        part[t] += v;
        __syncthreads();
    }
    int run = (t == 0) ? 0 : part[t - 1];
    for (int i = 0; i < CPT; ++i) {
        int idx = base + i;
        if (idx < NN) {
            offsets[idx] = run;
            cursor[idx] = run;
            run += counts[idx];
        }
    }
    if (t == SCAN_T - 1) offsets[NN] = run;
}

// ---------------------------------------------------------------------------
// k_sm: fused scatter (blocks [0, 2344)) + node MLP (blocks [2344, 2657)).
// Scatter materializes dst-sorted 64B edge records:
//   dwords: {src, dst, ev0, ev1, ev2, q0..q10}  (q = fp16-packed es*fc + {fc,0})
// MLP: gnh low halves = bf16( silu(nsb@Wm1+bm1) @ Wm2 + bm2 )
// ---------------------------------------------------------------------------
#define SCAT_B 2344
__global__ __launch_bounds__(256) void k_sm(
    const int* __restrict__ eidx, int* __restrict__ cursor,
    const float* __restrict__ es, const float* __restrict__ enorm,
    const float* __restrict__ evec, unsigned* __restrict__ rec,
    const unsigned short* __restrict__ nsb,
    const unsigned short* __restrict__ Wm1p, const float* __restrict__ bm1,
    const unsigned short* __restrict__ Wm2p, const float* __restrict__ bm2,
    unsigned* __restrict__ gnh) {
    __shared__ unsigned short lsh[4][16][136];
    if (blockIdx.x < SCAT_B) {
        int e = blockIdx.x * 256 + threadIdx.x;
        if (e < NE) {
            int s  = eidx[2 * e];
            int dd = eidx[2 * e + 1];
            float nrm = enorm[e];
            float fc = (nrm < CUT) ? 0.5f * (__cosf(PI_F * nrm * (1.0f / CUT)) + 1.0f) : 0.0f;
            const float* er = es + (long)e * ESZ;
            unsigned qv[11];
#pragma unroll
            for (int p = 0; p < 10; ++p)
                qv[p] = pack2h(er[2 * p] * fc, er[2 * p + 1] * fc);
            qv[10] = pack2h(fc, 0.f);
            float e0 = evec[3 * e + 0], e1 = evec[3 * e + 1], e2 = evec[3 * e + 2];
            int pos = atomicAdd(&cursor[dd], 1);
            uint4* rp = (uint4*)rec + (long)pos * 4;
            rp[0] = make_uint4((unsigned)s, (unsigned)dd,
                               __float_as_uint(e0), __float_as_uint(e1));
            rp[1] = make_uint4(__float_as_uint(e2), qv[0], qv[1], qv[2]);
            rp[2] = make_uint4(qv[3], qv[4], qv[5], qv[6]);
            rp[3] = make_uint4(qv[7], qv[8], qv[9], qv[10]);
        }
        return;
    }
    const int lane = threadIdx.x & 63;
    const int wv = threadIdx.x >> 6;
    const int wid = (blockIdx.x - SCAT_B) * 4 + wv;
    const int m0 = wid * 16;
    if (m0 >= NN) return;
    const int ml = lane & 15, q = lane >> 4;

    short8 a1[4];
#pragma unroll
    for (int kb = 0; kb < 4; ++kb)
        a1[kb] = *(const short8*)(nsb + (long)(m0 + ml) * ND + kb * 32 + q * 8);

#pragma unroll
    for (int nt = 0; nt < 8; ++nt) {
        float b = bm1[nt * 16 + ml];
        f32x4 acc = {b, b, b, b};
#pragma unroll
        for (int kb = 0; kb < 4; ++kb) {
            short8 bf = *(const short8*)(Wm1p + ((nt * 4 + kb) * 64 + lane) * 8);
            acc = __builtin_amdgcn_mfma_f32_16x16x32_bf16(a1[kb], bf, acc, 0, 0, 0);
        }
#pragma unroll
        for (int r = 0; r < 4; ++r)
            lsh[wv][q * 4 + r][nt * 16 + ml] = f2bf(silu_f(acc[r]));
    }
    __syncthreads();

    short8 a2[4];
#pragma unroll
    for (int kb = 0; kb < 4; ++kb)
        a2[kb] = *(const short8*)(&lsh[wv][ml][kb * 32 + q * 8]);

    unsigned short* gs = (unsigned short*)gnh;
#pragma unroll
    for (int nt = 0; nt < 24; ++nt) {
        float b = bm2[nt * 16 + ml];
        f32x4 acc = {b, b, b, b};
#pragma unroll
        for (int kb = 0; kb < 4; ++kb) {
            short8 bf = *(const short8*)(Wm2p + ((nt * 4 + kb) * 64 + lane) * 8);
            acc = __builtin_amdgcn_mfma_f32_16x16x32_bf16(a2[kb], bf, acc, 0, 0, 0);
        }
#pragma unroll
        for (int r = 0; r < 4; ++r) {
            long idx = (long)(m0 + q * 4 + r) * 384 + nt * 16 + ml;
            gs[idx * 2] = f2bf(acc[r]);   // low half of gnh
        }
    }
}

// ---------------------------------------------------------------------------
// k_edge9: dst-owning groups. One group (2 waves, 128 channels) owns 4
// consecutive dst nodes via CSR offsets. Inner loop over the group's edge
// stream is BRANCH-FREE in vmcnt ops:
//   - payload: uniform-address dwordx4 loads direct from rec (prefetch +2,
//     clamped to a zeroed pad record past len -> tail steps contribute 0);
//   - gather: ring depth 4, static slots (unroll 4); src ids come from 3
//     per-lane vector loads (192 edges) extracted via v_readlane;
//   - segment boundary: wave-uniform branch containing ONLY LDS writes +
//     VALU resets (lgkm queue) -> vmcnt counting stays path-independent;
//   - output: plain stores of ns/nsv + acc (group owns dsts; no atomics).
// ---------------------------------------------------------------------------
#define NDST 4
#define EMAX 192
#define NGRP9 (NN / NDST)   // 5000 groups, 2500 blocks

#define RL(v, j) __builtin_amdgcn_readlane((int)(v), (j))

#define FLS(sg) {                                                             \
    fsl[gl][sg][0][t] = as;                                                   \
    fsl[gl][sg][1][t] = av0;                                                  \
    fsl[gl][sg][2][t] = av1;                                                  \
    fsl[gl][sg][3][t] = av2;                                                  \
}

#define BCHK(k) {                                                             \
    while ((k) == b_next) {                                                   \
        FLS(seg);                                                             \
        as = 0.f; av0 = 0.f; av1 = 0.f; av2 = 0.f;                            \
        ++seg;                                                                \
        b_next = (seg == 1) ? B2 : (seg == 2) ? B3 : 0x7fffffff;              \
    }                                                                         \
}

#define ECOMP(M0_, M1_, M2_, M3_, XA_, XB_, XC_) {                            \
    unsigned ea_[11] = {M1_.y, M1_.z, M1_.w, M2_.x, M2_.y, M2_.z, M2_.w,      \
                        M3_.x, M3_.y, M3_.z, M3_.w};                          \
    float f0 = 0.f, f1 = 0.f, f2 = 0.f;                                       \
    _Pragma("unroll")                                                         \
    for (int p = 0; p < 11; ++p) {                                            \
        f0 = dot2u(ea_[p], wf[p][0], f0);                                     \
        f1 = dot2u(ea_[p], wf[p][1], f1);                                     \
        f2 = dot2u(ea_[p], wf[p][2], f2);                                     \
    }                                                                         \
    f0 *= __uint_as_float(XA_ << 16);                                         \
    f1 *= __uint_as_float(XB_ << 16);                                         \
    f2 *= __uint_as_float(XC_ << 16);                                         \
    as  += f2;                                                                \
    av0 += __uint_as_float(XA_ & 0xffff0000u) * f0 + f1 * __uint_as_float(M0_.z); \
    av1 += __uint_as_float(XB_ & 0xffff0000u) * f0 + f1 * __uint_as_float(M0_.w); \
    av2 += __uint_as_float(XC_ & 0xffff0000u) * f0 + f1 * __uint_as_float(M1_.x); \
}

#define ESTEP(k, s) {                                                         \
    BCHK(k)                                                                   \
    const uint4 M0_ = pq[(s) & 1][0], M1_ = pq[(s) & 1][1],                   \
                M2_ = pq[(s) & 1][2], M3_ = pq[(s) & 1][3];                   \
    const unsigned XA_ = xr[s][0], XB_ = xr[s][1], XC_ = xr[s][2];            \
    { const int kp_ = (k) + 2;                                                \
      const unsigned* pa_ = (kp_ < fl) ? rb + (long)kp_ * 16 : zrec;          \
      pq[(s) & 1][0] = *(const uint4*)(pa_);                                  \
      pq[(s) & 1][1] = *(const uint4*)(pa_ + 4);                              \
      pq[(s) & 1][2] = *(const uint4*)(pa_ + 8);                              \
      pq[(s) & 1][3] = *(const uint4*)(pa_ + 12); }                           \
    { int kg_ = (k) + 4; if (kg_ > EMAX - 1) kg_ = EMAX - 1;                  \
      const int ln_ = kg_ & 63;                                               \
      int sg_ = RL(srcA, ln_);                                                \
      sg_ = (kg_ >= 64)  ? RL(srcB, ln_) : sg_;                               \
      sg_ = (kg_ >= 128) ? RL(srcC, ln_) : sg_;                               \
      const unsigned* gp_ = gnh + (long)sg_ * 384;                            \
      xr[s][0] = gp_[t]; xr[s][1] = gp_[128 + t]; xr[s][2] = gp_[256 + t]; }  \
    ECOMP(M0_, M1_, M2_, M3_, XA_, XB_, XC_)                                  \
}

__global__ __launch_bounds__(256, 4) void k_edge9(
    const unsigned* __restrict__ rec, const unsigned* __restrict__ wfh,
    const unsigned* __restrict__ gnh, const int* __restrict__ offs,
    const float* __restrict__ ns, const float* __restrict__ nsv,
    float* __restrict__ out_s, float* __restrict__ out_v) {
    __shared__ float fsl[2][NDST][4][128];   // flush slots, 16 KB
    const int wv = threadIdx.x >> 6;
    const int lane = threadIdx.x & 63;
    const int gl = wv >> 1;                  // group slot in block
    const int grp = blockIdx.x * 2 + gl;     // 0..4999
    const int t = ((wv & 1) << 6) | lane;    // channel 0..127
    const int d0n = grp * NDST;

    hh2 wf[11][3];
#pragma unroll
    for (int p = 0; p < 11; ++p)
#pragma unroll
        for (int c = 0; c < 3; ++c)
            wf[p][c] = __builtin_bit_cast(hh2, wfh[p * 384 + c * 128 + t]);

    const int boff = offs[d0n];
    const int B1 = offs[d0n + 1] - boff;
    const int B2 = offs[d0n + 2] - boff;
    const int B3 = offs[d0n + 3] - boff;
    const int len = offs[d0n + 4] - boff;
    const unsigned* rb = rec + (long)boff * 16;
    const unsigned* zrec = rec + (long)NE * 16;   // zeroed pad record

    // src id vectors: lane l -> src of edges l, l+64, l+128 (pad-covered)
    unsigned srcA = rb[lane * 16];
    unsigned srcB = rb[(lane + 64) * 16];
    unsigned srcC = rb[(lane + 128) * 16];

    const int fl = (len < EMAX) ? len : EMAX;

    // prime payloads (edges 0,1) and gather ring (edges 0..3)
    uint4 pq[2][4];
    {
        const unsigned* pa0 = (0 < fl) ? rb : zrec;
        const unsigned* pa1 = (1 < fl) ? rb + 16 : zrec;
        pq[0][0] = *(const uint4*)(pa0);      pq[0][1] = *(const uint4*)(pa0 + 4);
        pq[0][2] = *(const uint4*)(pa0 + 8);  pq[0][3] = *(const uint4*)(pa0 + 12);
        pq[1][0] = *(const uint4*)(pa1);      pq[1][1] = *(const uint4*)(pa1 + 4);
        pq[1][2] = *(const uint4*)(pa1 + 8);  pq[1][3] = *(const uint4*)(pa1 + 12);
    }
    unsigned xr[4][3];
#pragma unroll
    for (int k = 0; k < 4; ++k) {
        int sgp = RL(srcA, k);
        const unsigned* gp = gnh + (long)sgp * 384;
        xr[k][0] = gp[t]; xr[k][1] = gp[128 + t]; xr[k][2] = gp[256 + t];
    }

    int seg = 0;
    int b_next = B1;
    float as = 0.f, av0 = 0.f, av1 = 0.f, av2 = 0.f;

    const int nit = (fl + 3) >> 2;
#pragma clang loop unroll(disable)
    for (int it = 0; it < nit; ++it) {
        const int k0 = it * 4;
        ESTEP(k0 + 0, 0)
        ESTEP(k0 + 1, 1)
        ESTEP(k0 + 2, 2)
        ESTEP(k0 + 3, 3)
    }

    // slow tail for pathological degree sums (P ~ 1e-10; correctness only)
    if (len > EMAX) {
        for (int k = EMAX; k < len; ++k) {
            BCHK(k)
            const unsigned* pa = rb + (long)k * 16;
            uint4 m0 = *(const uint4*)(pa),     m1 = *(const uint4*)(pa + 4);
            uint4 m2 = *(const uint4*)(pa + 8), m3 = *(const uint4*)(pa + 12);
            const unsigned* gp = gnh + (long)m0.x * 384;
            unsigned xa = gp[t], xb = gp[128 + t], xc = gp[256 + t];
            ECOMP(m0, m1, m2, m3, xa, xb, xc)
        }
    }

    // epilogue: flush current acc, zero-fill remaining slots, write outputs
    FLS(seg);
    as = 0.f; av0 = 0.f; av1 = 0.f; av2 = 0.f;
    for (int i = seg + 1; i < NDST; ++i) FLS(i);

#pragma unroll
    for (int d = 0; d < NDST; ++d) {
        const long node = d0n + d;
        float s0 = fsl[gl][d][0][t];
        float v0 = fsl[gl][d][1][t];
        float v1 = fsl[gl][d][2][t];
        float v2 = fsl[gl][d][3][t];
        out_s[node * ND + t]            = ns[node * ND + t] + s0;
        out_v[node * 384 + 0 * ND + t]  = nsv[node * 384 + 0 * ND + t] + v0;
        out_v[node * 384 + 1 * ND + t]  = nsv[node * 384 + 1 * ND + t] + v1;
        out_v[node * 384 + 2 * ND + t]  = nsv[node * 384 + 2 * ND + t] + v2;
    }
}

// ---------------------------------------------------------------------------
// k_tail: fused uvm+att. One wave owns 16 nodes end-to-end; cat and hidden
// live in wave-private LDS (no __syncthreads); ip stays in f32 regs;
// Uv stays as packed bf16 regs (same C-layout at produce and consume).
// ---------------------------------------------------------------------------
__global__ __launch_bounds__(256) void k_tail(
    const unsigned short* __restrict__ WUp, const unsigned short* __restrict__ WVp,
    const unsigned short* __restrict__ Wa1p, const float* __restrict__ ba1,
    const unsigned short* __restrict__ Wa2p, const float* __restrict__ ba2,
    float* __restrict__ out_s, float* __restrict__ out_v) {
    const int lane = threadIdx.x & 63;
    const int wv = threadIdx.x >> 6;
    const int wid = blockIdx.x * 4 + wv;
    const int m0 = wid * 16;
    if (m0 >= NN) return;
    const int ml = lane & 15, q = lane >> 4;
    __shared__ unsigned short ct[4][16][264];   // cat [s | vsq]
    __shared__ unsigned short hl[4][16][136];   // hidden

    // phase 1a: s-half of cat -> LDS (float2 load, packed bf16 dword write)
#pragma unroll
    for (int j = 0; j < 16; ++j) {
        int idx = j * 64 + lane;
        int n = idx >> 6, c2 = idx & 63;
        float2 sv = *(const float2*)(out_s + (long)(m0 + n) * 128 + c2 * 2);
        *(unsigned*)&ct[wv][n][c2 * 2] = pack2bf(sv.x, sv.y);
    }

    // phase 1b: A-frags of v
    short8 av[3][4];
#pragma unroll
    for (int ax = 0; ax < 3; ++ax)
#pragma unroll
        for (int kb = 0; kb < 4; ++kb) {
            const float* p = out_v + (long)(m0 + ml) * 384 + ax * 128 + kb * 32 + q * 8;
            float4 x = *(const float4*)p;
            float4 y = *(const float4*)(p + 4);
            short8 s;
            s[0] = (short)f2bf(x.x); s[1] = (short)f2bf(x.y);
            s[2] = (short)f2bf(x.z); s[3] = (short)f2bf(x.w);
            s[4] = (short)f2bf(y.x); s[5] = (short)f2bf(y.y);
            s[6] = (short)f2bf(y.z); s[7] = (short)f2bf(y.w);
            av[ax][kb] = s;
        }

    // phase 1c: Uv/Vv MFMA; vsq -> LDS, ip -> regs, Uv -> packed bf16 regs
    f32x4 ipr[8];
    unsigned upk[8][3][2];
#pragma unroll
    for (int nt = 0; nt < 8; ++nt) {
        f32x4 u0 = {0.f,0.f,0.f,0.f}, u1 = u0, u2 = u0;
        f32x4 v0 = u0, v1 = u0, v2 = u0;
#pragma unroll
        for (int kb = 0; kb < 4; ++kb) {
            short8 bu = *(const short8*)(WUp + ((nt * 4 + kb) * 64 + lane) * 8);
            short8 bv = *(const short8*)(WVp + ((nt * 4 + kb) * 64 + lane) * 8);
            u0 = __builtin_amdgcn_mfma_f32_16x16x32_bf16(av[0][kb], bu, u0, 0, 0, 0);
            u1 = __builtin_amdgcn_mfma_f32_16x16x32_bf16(av[1][kb], bu, u1, 0, 0, 0);
            u2 = __builtin_amdgcn_mfma_f32_16x16x32_bf16(av[2][kb], bu, u2, 0, 0, 0);
            v0 = __builtin_amdgcn_mfma_f32_16x16x32_bf16(av[0][kb], bv, v0, 0, 0, 0);
            v1 = __builtin_amdgcn_mfma_f32_16x16x32_bf16(av[1][kb], bv, v1, 0, 0, 0);
            v2 = __builtin_amdgcn_mfma_f32_16x16x32_bf16(av[2][kb], bv, v2, 0, 0, 0);
        }
        const int c = nt * 16 + ml;
#pragma unroll
        for (int r = 0; r < 4; ++r) {
            float vs  = v0[r] * v0[r] + v1[r] * v1[r] + v2[r] * v2[r];
            ct[wv][q * 4 + r][128 + c] = f2bf(vs);
            ipr[nt][r] = u0[r] * v0[r] + u1[r] * v1[r] + u2[r] * v2[r];
        }
        upk[nt][0][0] = pack2bf(u0[0], u0[1]); upk[nt][0][1] = pack2bf(u0[2], u0[3]);
        upk[nt][1][0] = pack2bf(u1[0], u1[1]); upk[nt][1][1] = pack2bf(u1[2], u1[3]);
        upk[nt][2][0] = pack2bf(u2[0], u2[1]); upk[nt][2][1] = pack2bf(u2[2], u2[3]);
    }

    // phase 2a: a1 frags from cat (wave-private LDS, in-order DS => no barrier)
    short8 a1[8];
#pragma unroll
    for (int kb = 0; kb < 8; ++kb)
        a1[kb] = *(const short8*)(&ct[wv][ml][kb * 32 + q * 8]);

#pragma unroll
    for (int nt = 0; nt < 8; ++nt) {
        float b = ba1[nt * 16 + ml];
        f32x4 acc = {b, b, b, b};
#pragma unroll
        for (int kb = 0; kb < 8; ++kb) {
            short8 bf = *(const short8*)(Wa1p + ((nt * 8 + kb) * 64 + lane) * 8);
            acc = __builtin_amdgcn_mfma_f32_16x16x32_bf16(a1[kb], bf, acc, 0, 0, 0);
        }
#pragma unroll
        for (int r = 0; r < 4; ++r)
            hl[wv][q * 4 + r][nt * 16 + ml] = f2bf(silu_f(acc[r]));
    }

    short8 h[4];
#pragma unroll
    for (int kb = 0; kb < 4; ++kb)
        h[kb] = *(const short8*)(&hl[wv][ml][kb * 32 + q * 8]);

#pragma unroll
    for (int nt = 0; nt < 8; ++nt) {
        float b0 = ba2[nt * 16 + ml];
        float b1 = ba2[128 + nt * 16 + ml];
        f32x4 aS = {b0, b0, b0, b0};
        f32x4 aG = {b1, b1, b1, b1};
#pragma unroll
        for (int kb = 0; kb < 4; ++kb) {
            short8 bS = *(const short8*)(Wa2p + (((nt) * 4 + kb) * 64 + lane) * 8);
            short8 bG = *(const short8*)(Wa2p + (((nt + 8) * 4 + kb) * 64 + lane) * 8);
            aS = __builtin_amdgcn_mfma_f32_16x16x32_bf16(h[kb], bS, aS, 0, 0, 0);
            aG = __builtin_amdgcn_mfma_f32_16x16x32_bf16(h[kb], bG, aG, 0, 0, 0);
        }
#pragma unroll
        for (int r = 0; r < 4; ++r) {
            long grow = m0 + q * 4 + r;
            long o = grow * 128 + nt * 16 + ml;
            out_s[o] = out_s[o] + aS[r] + aG[r] * ipr[nt][r];
        }
    }

#pragma unroll
    for (int nt = 0; nt < 8; ++nt) {
        float b2 = ba2[256 + nt * 16 + ml];
        f32x4 aV = {b2, b2, b2, b2};
#pragma unroll
        for (int kb = 0; kb < 4; ++kb) {
            short8 bV = *(const short8*)(Wa2p + (((nt + 16) * 4 + kb) * 64 + lane) * 8);
            aV = __builtin_amdgcn_mfma_f32_16x16x32_bf16(h[kb], bV, aV, 0, 0, 0);
        }
#pragma unroll
        for (int r = 0; r < 4; ++r) {
            long grow = m0 + q * 4 + r;
            int c = nt * 16 + ml;
#pragma unroll
            for (int ax = 0; ax < 3; ++ax) {
                unsigned pk = upk[nt][ax][r >> 1];
                unsigned short uh = (r & 1) ? (unsigned short)(pk >> 16)
                                            : (unsigned short)(pk & 0xffffu);
                long o = grow * 384 + ax * 128 + c;
                out_v[o] = out_v[o] + aV[r] * bf2f(uh);
            }
        }
    }
}

// ---------------------------------------------------------------------------
extern "C" void kernel_launch(void* const* d_in, const int* in_sizes, int n_in,
                              void* d_out, int out_size, void* d_ws, size_t ws_size,
                              hipStream_t stream) {
    const float* ns    = (const float*)d_in[0];
    const float* nsv   = (const float*)d_in[1];
    const float* es    = (const float*)d_in[2];
    const float* evec  = (const float*)d_in[3];
    const float* enorm = (const float*)d_in[4];
    const int*   eidx  = (const int*)d_in[5];
    const float* Wf    = (const float*)d_in[6];
    const float* bfb   = (const float*)d_in[7];
    const float* Wm1   = (const float*)d_in[8];
    const float* bm1   = (const float*)d_in[9];
    const float* Wm2   = (const float*)d_in[10];
    const float* bm2   = (const float*)d_in[11];
    const float* WU    = (const float*)d_in[12];
    const float* WV    = (const float*)d_in[13];
    const float* Wa1   = (const float*)d_in[14];
    const float* ba1   = (const float*)d_in[15];
    const float* Wa2   = (const float*)d_in[16];
    const float* ba2   = (const float*)d_in[17];

    float* out_s = (float*)d_out;
    float* out_v = out_s + (size_t)NN * ND;

    // ---- workspace layout ----
    char* w = (char*)d_ws;
    unsigned short* p1  = (unsigned short*)(w + 0);        //  32,768 B
    unsigned short* p2  = (unsigned short*)(w + 32768);    //  98,304 B
    unsigned short* pU  = (unsigned short*)(w + 131072);   //  32,768 B
    unsigned short* pV  = (unsigned short*)(w + 163840);   //  32,768 B
    unsigned short* pa1 = (unsigned short*)(w + 196608);   //  65,536 B
    unsigned short* pa2 = (unsigned short*)(w + 262144);   //  98,304 B
    unsigned* wfh = (unsigned*)(w + 360448);               //  16,896 B
    int* counts = (int*)(w + 377344);                      //  80,000 B
    int* offs   = (int*)(w + 457344);                      //  80,004 B
    int* cursor = (int*)(w + 537408);                      //  80,000 B
    // dst-sorted 64B edge records + 192 zeroed pad records
    unsigned* rec = (unsigned*)(w + 617408);               // 38,412,288 B
    char* u0 = w + 39029696;
    unsigned* gnh       = (unsigned*)(u0);                     // 30,720,000 B
    unsigned short* nsb = (unsigned short*)(u0 + 30720000);    //  5,120,000 B

    hipMemsetAsync(counts, 0, (size_t)NN * sizeof(int), stream);
    hipMemsetAsync(rec + (size_t)NE * 16, 0, 192 * 64, stream);  // zero pad records
    k_front<<<(int)((R3 + 255) / 256), 256, 0, stream>>>(
        (const float4*)ns, (const float4*)nsv, eidx, Wf, bfb,
        Wm1, Wm2, WU, WV, Wa1, Wa2,
        (ushort4*)nsb, gnh,
        p1, p2, pU, pV, pa1, pa2, wfh, counts);
    k_scan<<<1, SCAN_T, 0, stream>>>(counts, offs, cursor);
    k_sm<<<SCAT_B + 313, 256, 0, stream>>>(eidx, cursor, es, enorm, evec, rec,
                                           nsb, p1, bm1, p2, bm2, gnh);
    k_edge9<<<NGRP9 / 2, 256, 0, stream>>>(rec, wfh, gnh, offs, ns, nsv,
                                           out_s, out_v);
    k_tail<<<313, 256, 0, stream>>>(pU, pV, pa1, ba1, pa2, ba2, out_s, out_v);
}

// Round 6
// 468.017 us; speedup vs baseline: 1.1271x; 1.1271x over previous
//
#include <hip/hip_runtime.h>

#define ND 128          // NODE_SIZE
#define ESZ 20          // EDGE_SIZE
#define NN 20000        // N_NODES
#define NE 600000       // N_EDGES
#define PI_F 3.14159265358979323846f
#define CUT 5.0f

using short8 = __attribute__((ext_vector_type(8))) short;   // 8 bf16 (4 VGPR)
using f32x4  = __attribute__((ext_vector_type(4))) float;   // MFMA C/D
using hh2    = __attribute__((ext_vector_type(2))) _Float16;

__device__ __forceinline__ float silu_f(float x) { return x / (1.0f + __expf(-x)); }

__device__ __forceinline__ unsigned short f2bf(float x) {
    unsigned u = __float_as_uint(x);
    unsigned r = (u + 0x7FFFu + ((u >> 16) & 1u)) >> 16;
    return (unsigned short)r;
}
__device__ __forceinline__ float bf2f(unsigned short h) {
    return __uint_as_float(((unsigned)h) << 16);
}
__device__ __forceinline__ unsigned pack2bf(float x, float y) {
    return (unsigned)f2bf(x) | ((unsigned)f2bf(y) << 16);
}
__device__ __forceinline__ unsigned pack2h(float x, float y) {
    _Float16 a = (_Float16)x, b = (_Float16)y;
    unsigned short ua = __builtin_bit_cast(unsigned short, a);
    unsigned short ub = __builtin_bit_cast(unsigned short, b);
    return (unsigned)ua | ((unsigned)ub << 16);
}
__device__ __forceinline__ float dot2u(unsigned a, hh2 b, float acc) {
    return __builtin_amdgcn_fdot2(__builtin_bit_cast(hh2, a), b, acc, false);
}

// ---------------------------------------------------------------------------
// weight pack helper (bf16 B-fragment layout for 16x16x32 MFMA)
// ---------------------------------------------------------------------------
__device__ __forceinline__ void pack_w(const float* __restrict__ W,
                                       unsigned short* __restrict__ P,
                                       int s, int K, int N) {
    int k = s / N, n = s - k * N;
    int dst = ((((n >> 4) * (K >> 5) + (k >> 5)) * 64) +
               (((k >> 3) & 3) << 4) + (n & 15)) * 8 + (k & 7);
    P[dst] = f2bf(W[s]);
}

// ---------------------------------------------------------------------------
// k_front: fused prep (node copy (out pre-fill for edge atomics) + nsb pack,
// weight packs, Wf fp16 pack (11 rows), dst histogram). gnh writes moved
// entirely into k_sm's MLP (full-dword fused write).
// ---------------------------------------------------------------------------
#define R0 1920000L
#define R1 (R0 + 180224L)
#define R2 (R1 + 4224L)
#define R3 (R2 + 600000L)

__global__ __launch_bounds__(256) void k_front(
    const float4* __restrict__ ns4, const float4* __restrict__ nsv4,
    const int* __restrict__ eidx,
    const float* __restrict__ Wf, const float* __restrict__ bfb,
    const float* __restrict__ Wm1, const float* __restrict__ Wm2,
    const float* __restrict__ WU, const float* __restrict__ WV,
    const float* __restrict__ Wa1, const float* __restrict__ Wa2,
    float4* __restrict__ outs4, float4* __restrict__ outv4,
    ushort4* __restrict__ nsb4,
    unsigned short* __restrict__ p1, unsigned short* __restrict__ p2,
    unsigned short* __restrict__ pU, unsigned short* __restrict__ pV,
    unsigned short* __restrict__ pa1, unsigned short* __restrict__ pa2,
    unsigned* __restrict__ wfh, int* __restrict__ counts) {
    long gid = (long)blockIdx.x * 256 + threadIdx.x;
    if (gid < R0) {
        long i = gid;
        const long S4 = (long)NN * ND / 4;
        if (i < S4) {
            float4 v = ns4[i];
            outs4[i] = v;
            ushort4 h; h.x = f2bf(v.x); h.y = f2bf(v.y); h.z = f2bf(v.z); h.w = f2bf(v.w);
            nsb4[i] = h;
        }
        outv4[i] = nsv4[i];
    } else if (gid < R1) {
        int i = (int)(gid - R0);
        if      (i <  16384) pack_w(Wm1, p1, i,          128, 128);
        else if (i <  65536) pack_w(Wm2, p2, i - 16384,  128, 384);
        else if (i <  81920) pack_w(WU,  pU, i - 65536,  128, 128);
        else if (i <  98304) pack_w(WV,  pV, i - 81920,  128, 128);
        else if (i < 131072) pack_w(Wa1, pa1, i - 98304, 256, 128);
        else                 pack_w(Wa2, pa2, i - 131072,128, 384);
    } else if (gid < R2) {
        int j = (int)(gid - R1);        // 11*384
        int p = j / 384, cc = j - p * 384;
        float a = 0.f, b = 0.f;
        if (p < 10) { a = Wf[(2 * p) * 384 + cc]; b = Wf[(2 * p + 1) * 384 + cc]; }
        else if (p == 10) { a = bfb[cc]; }
        wfh[p * 384 + cc] = pack2h(a, b);
    } else if (gid < R3) {
        int e = (int)(gid - R2);
        atomicAdd(&counts[eidx[2 * e + 1]], 1);
    }
}

// ---------------------------------------------------------------------------
// CSR scan
// ---------------------------------------------------------------------------
#define SCAN_T 1024
__global__ __launch_bounds__(SCAN_T) void k_scan(const int* __restrict__ counts,
                                                 int* __restrict__ offsets,
                                                 int* __restrict__ cursor) {
    __shared__ int part[SCAN_T];
    const int t = threadIdx.x;
    const int CPT = (NN + SCAN_T - 1) / SCAN_T;
    const int base = t * CPT;
    int sum = 0;
    for (int i = 0; i < CPT; ++i) {
        int idx = base + i;
        if (idx < NN) sum += counts[idx];
    }
    part[t] = sum;
    __syncthreads();
    for (int off = 1; off < SCAN_T; off <<= 1) {
        int v = (t >= off) ? part[t - off] : 0;
        __syncthreads();
        part[t] += v;
        __syncthreads();
    }
    int run = (t == 0) ? 0 : part[t - 1];
    for (int i = 0; i < CPT; ++i) {
        int idx = base + i;
        if (idx < NN) {
            offsets[idx] = run;
            cursor[idx] = run;
            run += counts[idx];
        }
    }
    if (t == SCAN_T - 1) offsets[NN] = run;
}

// ---------------------------------------------------------------------------
// k_sm: fused scatter (blocks [0, 2344)) + node MLP (blocks [2344, 2657)).
// Scatter materializes dst-sorted 64B edge records:
//   dwords: {src, dst, ev0, ev1, ev2, q0..q10}  (q = fp16-packed es*fc + {fc,0})
// MLP: gnh[idx] = (bf16(so[idx]) | bf16(nsv[idx]) << 16) -- FULL dword write
// (so = silu(nsb@Wm1+bm1)@Wm2+bm2; replaces the two half-dword passes).
// ---------------------------------------------------------------------------
#define SCAT_B 2344
__global__ __launch_bounds__(256) void k_sm(
    const int* __restrict__ eidx, int* __restrict__ cursor,
    const float* __restrict__ es, const float* __restrict__ enorm,
    const float* __restrict__ evec, unsigned* __restrict__ rec,
    const unsigned short* __restrict__ nsb, const float* __restrict__ nsv,
    const unsigned short* __restrict__ Wm1p, const float* __restrict__ bm1,
    const unsigned short* __restrict__ Wm2p, const float* __restrict__ bm2,
    unsigned* __restrict__ gnh) {
    __shared__ unsigned short lsh[4][16][136];
    if (blockIdx.x < SCAT_B) {
        int e = blockIdx.x * 256 + threadIdx.x;
        if (e < NE) {
            int s  = eidx[2 * e];
            int dd = eidx[2 * e + 1];
            float nrm = enorm[e];
            float fc = (nrm < CUT) ? 0.5f * (__cosf(PI_F * nrm * (1.0f / CUT)) + 1.0f) : 0.0f;
            const float* er = es + (long)e * ESZ;
            unsigned qv[11];
#pragma unroll
            for (int p = 0; p < 10; ++p)
                qv[p] = pack2h(er[2 * p] * fc, er[2 * p + 1] * fc);
            qv[10] = pack2h(fc, 0.f);
            float e0 = evec[3 * e + 0], e1 = evec[3 * e + 1], e2 = evec[3 * e + 2];
            int pos = atomicAdd(&cursor[dd], 1);
            uint4* rp = (uint4*)rec + (long)pos * 4;
            rp[0] = make_uint4((unsigned)s, (unsigned)dd,
                               __float_as_uint(e0), __float_as_uint(e1));
            rp[1] = make_uint4(__float_as_uint(e2), qv[0], qv[1], qv[2]);
            rp[2] = make_uint4(qv[3], qv[4], qv[5], qv[6]);
            rp[3] = make_uint4(qv[7], qv[8], qv[9], qv[10]);
        }
        return;
    }
    const int lane = threadIdx.x & 63;
    const int wv = threadIdx.x >> 6;
    const int wid = (blockIdx.x - SCAT_B) * 4 + wv;
    const int m0 = wid * 16;
    if (m0 >= NN) return;
    const int ml = lane & 15, q = lane >> 4;

    short8 a1[4];
#pragma unroll
    for (int kb = 0; kb < 4; ++kb)
        a1[kb] = *(const short8*)(nsb + (long)(m0 + ml) * ND + kb * 32 + q * 8);

#pragma unroll
    for (int nt = 0; nt < 8; ++nt) {
        float b = bm1[nt * 16 + ml];
        f32x4 acc = {b, b, b, b};
#pragma unroll
        for (int kb = 0; kb < 4; ++kb) {
            short8 bf = *(const short8*)(Wm1p + ((nt * 4 + kb) * 64 + lane) * 8);
            acc = __builtin_amdgcn_mfma_f32_16x16x32_bf16(a1[kb], bf, acc, 0, 0, 0);
        }
#pragma unroll
        for (int r = 0; r < 4; ++r)
            lsh[wv][q * 4 + r][nt * 16 + ml] = f2bf(silu_f(acc[r]));
    }
    __syncthreads();

    short8 a2[4];
#pragma unroll
    for (int kb = 0; kb < 4; ++kb)
        a2[kb] = *(const short8*)(&lsh[wv][ml][kb * 32 + q * 8]);

#pragma unroll
    for (int nt = 0; nt < 24; ++nt) {
        float b = bm2[nt * 16 + ml];
        f32x4 acc = {b, b, b, b};
#pragma unroll
        for (int kb = 0; kb < 4; ++kb) {
            short8 bf = *(const short8*)(Wm2p + ((nt * 4 + kb) * 64 + lane) * 8);
            acc = __builtin_amdgcn_mfma_f32_16x16x32_bf16(a2[kb], bf, acc, 0, 0, 0);
        }
#pragma unroll
        for (int r = 0; r < 4; ++r) {
            long idx = (long)(m0 + q * 4 + r) * 384 + nt * 16 + ml;
            gnh[idx] = (unsigned)f2bf(acc[r]) | ((unsigned)f2bf(nsv[idx]) << 16);
        }
    }
}

// ---------------------------------------------------------------------------
// k_edge7: chunk-unrolled segmented reduction, deep counted pipeline.
//   RUN=80 = 5 chunks x 16 edges; 600000/80 = 7500 groups exactly (no tails).
//   - (src,dst) of a whole chunk via one lane-indexed ds_read_b64 + readlane
//     -> SGPRs a chunk ahead of use (gather no longer waits on payload read).
//   - gnh gather ring, depth 8 edges (issued at STEP(k-8), counted vmcnt).
//   - payload 4x ds_read_b128 (uniform broadcast), double-buffered 2 ahead.
//   - record chunks staged reg->LDS one chunk ahead (vmcnt cover = 16 edges).
// ---------------------------------------------------------------------------
#define NGRP 7500
#define RUN 80

#define FLUSH() {                                                             \
    atomicAdd(&out_s[(long)cur_dst * ND + t], as);                            \
    atomicAdd(&out_v[(long)cur_dst * 384 + 0 * ND + t], av0);                 \
    atomicAdd(&out_v[(long)cur_dst * 384 + 1 * ND + t], av1);                 \
    atomicAdd(&out_v[(long)cur_dst * 384 + 2 * ND + t], av2);                 \
}

#define STEP(k, dk, gsrc) {                                                   \
    if (dk != cur_dst) {                                                      \
        if (cur_dst >= 0) FLUSH();                                            \
        cur_dst = dk;                                                         \
        as = 0.f; av0 = 0.f; av1 = 0.f; av2 = 0.f;                            \
    }                                                                         \
    const uint4 M0_ = pp[(k) & 1][0], M1_ = pp[(k) & 1][1],                   \
                M2_ = pp[(k) & 1][2], M3_ = pp[(k) & 1][3];                   \
    const unsigned XA_ = xr[(k) & 7][0], XB_ = xr[(k) & 7][1],                \
                   XC_ = xr[(k) & 7][2];                                      \
    /* refill payload with edge k+2 */                                        \
    { const unsigned* pb_ = (((k) + 2 < 16) ? bc : bn) + ((((k) + 2) & 15) << 4); \
      pp[(k) & 1][0] = *(const uint4*)(pb_);                                  \
      pp[(k) & 1][1] = *(const uint4*)(pb_ + 4);                              \
      pp[(k) & 1][2] = *(const uint4*)(pb_ + 8);                              \
      pp[(k) & 1][3] = *(const uint4*)(pb_ + 12); }                           \
    /* gather edge k+8 */                                                     \
    { const unsigned* gp_ = gnh + (long)(gsrc) * 384;                         \
      xr[(k) & 7][0] = gp_[t];                                                \
      xr[(k) & 7][1] = gp_[128 + t];                                          \
      xr[(k) & 7][2] = gp_[256 + t]; }                                        \
    unsigned ea_[11] = {M1_.y, M1_.z, M1_.w, M2_.x, M2_.y, M2_.z, M2_.w,      \
                        M3_.x, M3_.y, M3_.z, M3_.w};                          \
    float f0 = 0.f, f1 = 0.f, f2 = 0.f;                                       \
    _Pragma("unroll")                                                         \
    for (int p = 0; p < 11; ++p) {                                            \
        f0 = dot2u(ea_[p], wf[p][0], f0);                                     \
        f1 = dot2u(ea_[p], wf[p][1], f1);                                     \
        f2 = dot2u(ea_[p], wf[p][2], f2);                                     \
    }                                                                         \
    f0 *= __uint_as_float(XA_ << 16);                                         \
    f1 *= __uint_as_float(XB_ << 16);                                         \
    f2 *= __uint_as_float(XC_ << 16);                                         \
    as  += f2;                                                                \
    av0 += __uint_as_float(XA_ & 0xffff0000u) * f0 + f1 * __uint_as_float(M0_.z); \
    av1 += __uint_as_float(XB_ & 0xffff0000u) * f0 + f1 * __uint_as_float(M0_.w); \
    av2 += __uint_as_float(XC_ & 0xffff0000u) * f0 + f1 * __uint_as_float(M1_.x); \
}

#define RL(v, j) __builtin_amdgcn_readlane((int)(v), (j))

__global__ __launch_bounds__(256, 3) void k_edge7(
    const unsigned* __restrict__ rec, const unsigned* __restrict__ wfh,
    const unsigned* __restrict__ gnh,
    float* __restrict__ out_s, float* __restrict__ out_v) {
    __shared__ __align__(16) unsigned eb[4][2][256];   // per-wave dbuf chunks
    const int wv = threadIdx.x >> 6;
    const int lane = threadIdx.x & 63;
    const int grp = blockIdx.x * 2 + (wv >> 1);
    const int t = ((wv & 1) << 6) | lane;              // channel 0..127
    const long beg = (long)grp * RUN;

    hh2 wf[11][3];
#pragma unroll
    for (int p = 0; p < 11; ++p)
#pragma unroll
        for (int c = 0; c < 3; ++c)
            wf[p][c] = __builtin_bit_cast(hh2, wfh[p * 384 + c * 128 + t]);

    unsigned* const b0 = &eb[wv][0][0];
    unsigned* const b1 = &eb[wv][1][0];

    // prologue: stage chunks 0,1 into LDS (batched loads), hold chunk 2 in regs
    uint4 sA = *(const uint4*)(rec + (beg + 0)  * 16 + lane * 4);
    uint4 sB = *(const uint4*)(rec + (beg + 16) * 16 + lane * 4);
    uint4 st = *(const uint4*)(rec + (beg + 32) * 16 + lane * 4);
    *(uint4*)&b0[lane * 4] = sA;
    *(uint4*)&b1[lane * 4] = sB;
    uint2 sdC = *(const uint2*)&b0[(lane & 15) << 4];   // (src,dst) chunk 0
    uint2 sdN = *(const uint2*)&b1[(lane & 15) << 4];   // (src,dst) chunk 1

    uint4 pp[2][4];
    pp[0][0] = *(const uint4*)(b0 + 0);  pp[0][1] = *(const uint4*)(b0 + 4);
    pp[0][2] = *(const uint4*)(b0 + 8);  pp[0][3] = *(const uint4*)(b0 + 12);
    pp[1][0] = *(const uint4*)(b0 + 16); pp[1][1] = *(const uint4*)(b0 + 20);
    pp[1][2] = *(const uint4*)(b0 + 24); pp[1][3] = *(const uint4*)(b0 + 28);

    unsigned xr[8][3];
#define IG(j) { int s_ = RL(sdC.x, j);                                        \
                const unsigned* gp_ = gnh + (long)s_ * 384;                   \
                xr[j][0] = gp_[t]; xr[j][1] = gp_[128 + t];                   \
                xr[j][2] = gp_[256 + t]; }
    IG(0) IG(1) IG(2) IG(3) IG(4) IG(5) IG(6) IG(7)
#undef IG

    int cur_dst = -1;
    float as = 0.f, av0 = 0.f, av1 = 0.f, av2 = 0.f;

    for (int c = 0; c < 5; ++c) {
        unsigned* const bc = &eb[wv][c & 1][0];
        unsigned* const bn = &eb[wv][(c + 1) & 1][0];
        const int d0  = RL(sdC.y, 0),  d1  = RL(sdC.y, 1);
        const int d2  = RL(sdC.y, 2),  d3  = RL(sdC.y, 3);
        const int d4  = RL(sdC.y, 4),  d5  = RL(sdC.y, 5);
        const int d6  = RL(sdC.y, 6),  d7  = RL(sdC.y, 7);
        const int d8  = RL(sdC.y, 8),  d9  = RL(sdC.y, 9);
        const int d10 = RL(sdC.y, 10), d11 = RL(sdC.y, 11);
        const int d12 = RL(sdC.y, 12), d13 = RL(sdC.y, 13);
        const int d14 = RL(sdC.y, 14), d15 = RL(sdC.y, 15);
        const int s8  = RL(sdC.x, 8),  s9  = RL(sdC.x, 9);
        const int s10 = RL(sdC.x, 10), s11 = RL(sdC.x, 11);
        const int s12 = RL(sdC.x, 12), s13 = RL(sdC.x, 13);
        const int s14 = RL(sdC.x, 14), s15 = RL(sdC.x, 15);

        STEP(0, d0, s8)   STEP(1, d1, s9)   STEP(2, d2, s10)  STEP(3, d3, s11)
        STEP(4, d4, s12)  STEP(5, d5, s13)  STEP(6, d6, s14)  STEP(7, d7, s15)

        const int gm = (c < 4) ? -1 : 0;   // last chunk: clamp gathers to node 0
        const int n0 = RL(sdN.x, 0) & gm, n1 = RL(sdN.x, 1) & gm;
        const int n2 = RL(sdN.x, 2) & gm, n3 = RL(sdN.x, 3) & gm;
        const int n4 = RL(sdN.x, 4) & gm, n5 = RL(sdN.x, 5) & gm;
        const int n6 = RL(sdN.x, 6) & gm, n7 = RL(sdN.x, 7) & gm;

        STEP(8,  d8,  n0)  STEP(9,  d9,  n1)  STEP(10, d10, n2) STEP(11, d11, n3)
        STEP(12, d12, n4)  STEP(13, d13, n5)  STEP(14, d14, n6) STEP(15, d15, n7)

        if (c < 4) {
            *(uint4*)&bc[lane * 4] = st;                              // SW chunk c+2
            st = *(const uint4*)(rec + (beg + (long)(c + 3) * 16) * 16 + lane * 4);
            sdC = sdN;
            sdN = *(const uint2*)&bc[(lane & 15) << 4];               // sd chunk c+2
        }
    }
    FLUSH();
}

// ---------------------------------------------------------------------------
// k_tail: fused uvm+att. One wave owns 16 nodes end-to-end; cat and hidden
// live in wave-private LDS (no __syncthreads); ip stays in f32 regs;
// Uv stays as packed bf16 regs (same C-layout at produce and consume).
// ---------------------------------------------------------------------------
__global__ __launch_bounds__(256) void k_tail(
    const unsigned short* __restrict__ WUp, const unsigned short* __restrict__ WVp,
    const unsigned short* __restrict__ Wa1p, const float* __restrict__ ba1,
    const unsigned short* __restrict__ Wa2p, const float* __restrict__ ba2,
    float* __restrict__ out_s, float* __restrict__ out_v) {
    const int lane = threadIdx.x & 63;
    const int wv = threadIdx.x >> 6;
    const int wid = blockIdx.x * 4 + wv;
    const int m0 = wid * 16;
    if (m0 >= NN) return;
    const int ml = lane & 15, q = lane >> 4;
    __shared__ unsigned short ct[4][16][264];   // cat [s | vsq]
    __shared__ unsigned short hl[4][16][136];   // hidden

    // phase 1a: s-half of cat -> LDS (float2 load, packed bf16 dword write)
#pragma unroll
    for (int j = 0; j < 16; ++j) {
        int idx = j * 64 + lane;
        int n = idx >> 6, c2 = idx & 63;
        float2 sv = *(const float2*)(out_s + (long)(m0 + n) * 128 + c2 * 2);
        *(unsigned*)&ct[wv][n][c2 * 2] = pack2bf(sv.x, sv.y);
    }

    // phase 1b: A-frags of v
    short8 av[3][4];
#pragma unroll
    for (int ax = 0; ax < 3; ++ax)
#pragma unroll
        for (int kb = 0; kb < 4; ++kb) {
            const float* p = out_v + (long)(m0 + ml) * 384 + ax * 128 + kb * 32 + q * 8;
            float4 x = *(const float4*)p;
            float4 y = *(const float4*)(p + 4);
            short8 s;
            s[0] = (short)f2bf(x.x); s[1] = (short)f2bf(x.y);
            s[2] = (short)f2bf(x.z); s[3] = (short)f2bf(x.w);
            s[4] = (short)f2bf(y.x); s[5] = (short)f2bf(y.y);
            s[6] = (short)f2bf(y.z); s[7] = (short)f2bf(y.w);
            av[ax][kb] = s;
        }

    // phase 1c: Uv/Vv MFMA; vsq -> LDS, ip -> regs, Uv -> packed bf16 regs
    f32x4 ipr[8];
    unsigned upk[8][3][2];
#pragma unroll
    for (int nt = 0; nt < 8; ++nt) {
        f32x4 u0 = {0.f,0.f,0.f,0.f}, u1 = u0, u2 = u0;
        f32x4 v0 = u0, v1 = u0, v2 = u0;
#pragma unroll
        for (int kb = 0; kb < 4; ++kb) {
            short8 bu = *(const short8*)(WUp + ((nt * 4 + kb) * 64 + lane) * 8);
            short8 bv = *(const short8*)(WVp + ((nt * 4 + kb) * 64 + lane) * 8);
            u0 = __builtin_amdgcn_mfma_f32_16x16x32_bf16(av[0][kb], bu, u0, 0, 0, 0);
            u1 = __builtin_amdgcn_mfma_f32_16x16x32_bf16(av[1][kb], bu, u1, 0, 0, 0);
            u2 = __builtin_amdgcn_mfma_f32_16x16x32_bf16(av[2][kb], bu, u2, 0, 0, 0);
            v0 = __builtin_amdgcn_mfma_f32_16x16x32_bf16(av[0][kb], bv, v0, 0, 0, 0);
            v1 = __builtin_amdgcn_mfma_f32_16x16x32_bf16(av[1][kb], bv, v1, 0, 0, 0);
            v2 = __builtin_amdgcn_mfma_f32_16x16x32_bf16(av[2][kb], bv, v2, 0, 0, 0);
        }
        const int c = nt * 16 + ml;
#pragma unroll
        for (int r = 0; r < 4; ++r) {
            float vs  = v0[r] * v0[r] + v1[r] * v1[r] + v2[r] * v2[r];
            ct[wv][q * 4 + r][128 + c] = f2bf(vs);
            ipr[nt][r] = u0[r] * v0[r] + u1[r] * v1[r] + u2[r] * v2[r];
        }
        upk[nt][0][0] = pack2bf(u0[0], u0[1]); upk[nt][0][1] = pack2bf(u0[2], u0[3]);
        upk[nt][1][0] = pack2bf(u1[0], u1[1]); upk[nt][1][1] = pack2bf(u1[2], u1[3]);
        upk[nt][2][0] = pack2bf(u2[0], u2[1]); upk[nt][2][1] = pack2bf(u2[2], u2[3]);
    }

    // phase 2a: a1 frags from cat (wave-private LDS, in-order DS => no barrier)
    short8 a1[8];
#pragma unroll
    for (int kb = 0; kb < 8; ++kb)
        a1[kb] = *(const short8*)(&ct[wv][ml][kb * 32 + q * 8]);

#pragma unroll
    for (int nt = 0; nt < 8; ++nt) {
        float b = ba1[nt * 16 + ml];
        f32x4 acc = {b, b, b, b};
#pragma unroll
        for (int kb = 0; kb < 8; ++kb) {
            short8 bf = *(const short8*)(Wa1p + ((nt * 8 + kb) * 64 + lane) * 8);
            acc = __builtin_amdgcn_mfma_f32_16x16x32_bf16(a1[kb], bf, acc, 0, 0, 0);
        }
#pragma unroll
        for (int r = 0; r < 4; ++r)
            hl[wv][q * 4 + r][nt * 16 + ml] = f2bf(silu_f(acc[r]));
    }

    short8 h[4];
#pragma unroll
    for (int kb = 0; kb < 4; ++kb)
        h[kb] = *(const short8*)(&hl[wv][ml][kb * 32 + q * 8]);

#pragma unroll
    for (int nt = 0; nt < 8; ++nt) {
        float b0 = ba2[nt * 16 + ml];
        float b1 = ba2[128 + nt * 16 + ml];
        f32x4 aS = {b0, b0, b0, b0};
        f32x4 aG = {b1, b1, b1, b1};
#pragma unroll
        for (int kb = 0; kb < 4; ++kb) {
            short8 bS = *(const short8*)(Wa2p + (((nt) * 4 + kb) * 64 + lane) * 8);
            short8 bG = *(const short8*)(Wa2p + (((nt + 8) * 4 + kb) * 64 + lane) * 8);
            aS = __builtin_amdgcn_mfma_f32_16x16x32_bf16(h[kb], bS, aS, 0, 0, 0);
            aG = __builtin_amdgcn_mfma_f32_16x16x32_bf16(h[kb], bG, aG, 0, 0, 0);
        }
#pragma unroll
        for (int r = 0; r < 4; ++r) {
            long grow = m0 + q * 4 + r;
            long o = grow * 128 + nt * 16 + ml;
            out_s[o] = out_s[o] + aS[r] + aG[r] * ipr[nt][r];
        }
    }

#pragma unroll
    for (int nt = 0; nt < 8; ++nt) {
        float b2 = ba2[256 + nt * 16 + ml];
        f32x4 aV = {b2, b2, b2, b2};
#pragma unroll
        for (int kb = 0; kb < 4; ++kb) {
            short8 bV = *(const short8*)(Wa2p + (((nt + 16) * 4 + kb) * 64 + lane) * 8);
            aV = __builtin_amdgcn_mfma_f32_16x16x32_bf16(h[kb], bV, aV, 0, 0, 0);
        }
#pragma unroll
        for (int r = 0; r < 4; ++r) {
            long grow = m0 + q * 4 + r;
            int c = nt * 16 + ml;
#pragma unroll
            for (int ax = 0; ax < 3; ++ax) {
                unsigned pk = upk[nt][ax][r >> 1];
                unsigned short uh = (r & 1) ? (unsigned short)(pk >> 16)
                                            : (unsigned short)(pk & 0xffffu);
                long o = grow * 384 + ax * 128 + c;
                out_v[o] = out_v[o] + aV[r] * bf2f(uh);
            }
        }
    }
}

// ---------------------------------------------------------------------------
extern "C" void kernel_launch(void* const* d_in, const int* in_sizes, int n_in,
                              void* d_out, int out_size, void* d_ws, size_t ws_size,
                              hipStream_t stream) {
    const float* ns    = (const float*)d_in[0];
    const float* nsv   = (const float*)d_in[1];
    const float* es    = (const float*)d_in[2];
    const float* evec  = (const float*)d_in[3];
    const float* enorm = (const float*)d_in[4];
    const int*   eidx  = (const int*)d_in[5];
    const float* Wf    = (const float*)d_in[6];
    const float* bfb   = (const float*)d_in[7];
    const float* Wm1   = (const float*)d_in[8];
    const float* bm1   = (const float*)d_in[9];
    const float* Wm2   = (const float*)d_in[10];
    const float* bm2   = (const float*)d_in[11];
    const float* WU    = (const float*)d_in[12];
    const float* WV    = (const float*)d_in[13];
    const float* Wa1   = (const float*)d_in[14];
    const float* ba1   = (const float*)d_in[15];
    const float* Wa2   = (const float*)d_in[16];
    const float* ba2   = (const float*)d_in[17];

    float* out_s = (float*)d_out;
    float* out_v = out_s + (size_t)NN * ND;

    // ---- workspace layout ----
    char* w = (char*)d_ws;
    unsigned short* p1  = (unsigned short*)(w + 0);        //  32,768 B
    unsigned short* p2  = (unsigned short*)(w + 32768);    //  98,304 B
    unsigned short* pU  = (unsigned short*)(w + 131072);   //  32,768 B
    unsigned short* pV  = (unsigned short*)(w + 163840);   //  32,768 B
    unsigned short* pa1 = (unsigned short*)(w + 196608);   //  65,536 B
    unsigned short* pa2 = (unsigned short*)(w + 262144);   //  98,304 B
    unsigned* wfh = (unsigned*)(w + 360448);               //  16,896 B
    int* counts = (int*)(w + 377344);                      //  80,000 B
    int* offs   = (int*)(w + 457344);                      //  80,004 B
    int* cursor = (int*)(w + 537408);                      //  80,000 B
    // dst-sorted 64B edge records; padded to 600,112 edges for chunk prefetch
    unsigned* rec = (unsigned*)(w + 617408);               // 38,407,168 B
    char* u0 = w + 39024576;
    unsigned* gnh       = (unsigned*)(u0);                     // 30,720,000 B
    unsigned short* nsb = (unsigned short*)(u0 + 30720000);    //  5,120,000 B

    hipMemsetAsync(counts, 0, (size_t)NN * sizeof(int), stream);
    hipMemsetAsync(rec + (size_t)NE * 16, 0, 112 * 64, stream);  // zero pad records
    k_front<<<(int)((R3 + 255) / 256), 256, 0, stream>>>(
        (const float4*)ns, (const float4*)nsv, eidx, Wf, bfb,
        Wm1, Wm2, WU, WV, Wa1, Wa2,
        (float4*)out_s, (float4*)out_v, (ushort4*)nsb,
        p1, p2, pU, pV, pa1, pa2, wfh, counts);
    k_scan<<<1, SCAN_T, 0, stream>>>(counts, offs, cursor);
    k_sm<<<SCAT_B + 313, 256, 0, stream>>>(eidx, cursor, es, enorm, evec, rec,
                                           nsb, nsv, p1, bm1, p2, bm2, gnh);
    k_edge7<<<NGRP / 2, 256, 0, stream>>>(rec, wfh, gnh, out_s, out_v);
    k_tail<<<313, 256, 0, stream>>>(pU, pV, pa1, ba1, pa2, ba2, out_s, out_v);
}

// Round 7
// 466.683 us; speedup vs baseline: 1.1304x; 1.0029x over previous
//
#include <hip/hip_runtime.h>

#define ND 128          // NODE_SIZE
#define ESZ 20          // EDGE_SIZE
#define NN 20000        // N_NODES
#define NE 600000       // N_EDGES
#define PI_F 3.14159265358979323846f
#define CUT 5.0f

using short8 = __attribute__((ext_vector_type(8))) short;   // 8 bf16 (4 VGPR)
using f32x4  = __attribute__((ext_vector_type(4))) float;   // MFMA C/D
using hh2    = __attribute__((ext_vector_type(2))) _Float16;

__device__ __forceinline__ float silu_f(float x) { return x / (1.0f + __expf(-x)); }

__device__ __forceinline__ unsigned short f2bf(float x) {
    unsigned u = __float_as_uint(x);
    unsigned r = (u + 0x7FFFu + ((u >> 16) & 1u)) >> 16;
    return (unsigned short)r;
}
__device__ __forceinline__ float bf2f(unsigned short h) {
    return __uint_as_float(((unsigned)h) << 16);
}
__device__ __forceinline__ unsigned pack2bf(float x, float y) {
    return (unsigned)f2bf(x) | ((unsigned)f2bf(y) << 16);
}
__device__ __forceinline__ unsigned pack2h(float x, float y) {
    _Float16 a = (_Float16)x, b = (_Float16)y;
    unsigned short ua = __builtin_bit_cast(unsigned short, a);
    unsigned short ub = __builtin_bit_cast(unsigned short, b);
    return (unsigned)ua | ((unsigned)ub << 16);
}
__device__ __forceinline__ float dot2u(unsigned a, hh2 b, float acc) {
    return __builtin_amdgcn_fdot2(__builtin_bit_cast(hh2, a), b, acc, false);
}

// ---------------------------------------------------------------------------
// weight pack helper (bf16 B-fragment layout for 16x16x32 MFMA)
// ---------------------------------------------------------------------------
__device__ __forceinline__ void pack_w(const float* __restrict__ W,
                                       unsigned short* __restrict__ P,
                                       int s, int K, int N) {
    int k = s / N, n = s - k * N;
    int dst = ((((n >> 4) * (K >> 5) + (k >> 5)) * 64) +
               (((k >> 3) & 3) << 4) + (n & 15)) * 8 + (k & 7);
    P[dst] = f2bf(W[s]);
}

// ---------------------------------------------------------------------------
// k_front: fused prep (node copy (out pre-fill for edge atomics) + nsb pack,
// weight packs, Wf fp16 pack (11 rows), dst histogram). gnh is written once,
// as full dwords, in k_sm's MLP.
// ---------------------------------------------------------------------------
#define R0 1920000L
#define R1 (R0 + 180224L)
#define R2 (R1 + 4224L)
#define R3 (R2 + 600000L)

__global__ __launch_bounds__(256) void k_front(
    const float4* __restrict__ ns4, const float4* __restrict__ nsv4,
    const int* __restrict__ eidx,
    const float* __restrict__ Wf, const float* __restrict__ bfb,
    const float* __restrict__ Wm1, const float* __restrict__ Wm2,
    const float* __restrict__ WU, const float* __restrict__ WV,
    const float* __restrict__ Wa1, const float* __restrict__ Wa2,
    float4* __restrict__ outs4, float4* __restrict__ outv4,
    ushort4* __restrict__ nsb4,
    unsigned short* __restrict__ p1, unsigned short* __restrict__ p2,
    unsigned short* __restrict__ pU, unsigned short* __restrict__ pV,
    unsigned short* __restrict__ pa1, unsigned short* __restrict__ pa2,
    unsigned* __restrict__ wfh, int* __restrict__ counts) {
    long gid = (long)blockIdx.x * 256 + threadIdx.x;
    if (gid < R0) {
        long i = gid;
        const long S4 = (long)NN * ND / 4;
        if (i < S4) {
            float4 v = ns4[i];
            outs4[i] = v;
            ushort4 h; h.x = f2bf(v.x); h.y = f2bf(v.y); h.z = f2bf(v.z); h.w = f2bf(v.w);
            nsb4[i] = h;
        }
        outv4[i] = nsv4[i];
    } else if (gid < R1) {
        int i = (int)(gid - R0);
        if      (i <  16384) pack_w(Wm1, p1, i,          128, 128);
        else if (i <  65536) pack_w(Wm2, p2, i - 16384,  128, 384);
        else if (i <  81920) pack_w(WU,  pU, i - 65536,  128, 128);
        else if (i <  98304) pack_w(WV,  pV, i - 81920,  128, 128);
        else if (i < 131072) pack_w(Wa1, pa1, i - 98304, 256, 128);
        else                 pack_w(Wa2, pa2, i - 131072,128, 384);
    } else if (gid < R2) {
        int j = (int)(gid - R1);        // 11*384
        int p = j / 384, cc = j - p * 384;
        float a = 0.f, b = 0.f;
        if (p < 10) { a = Wf[(2 * p) * 384 + cc]; b = Wf[(2 * p + 1) * 384 + cc]; }
        else if (p == 10) { a = bfb[cc]; }
        wfh[p * 384 + cc] = pack2h(a, b);
    } else if (gid < R3) {
        int e = (int)(gid - R2);
        atomicAdd(&counts[eidx[2 * e + 1]], 1);
    }
}

// ---------------------------------------------------------------------------
// CSR scan
// ---------------------------------------------------------------------------
#define SCAN_T 1024
__global__ __launch_bounds__(SCAN_T) void k_scan(const int* __restrict__ counts,
                                                 int* __restrict__ offsets,
                                                 int* __restrict__ cursor) {
    __shared__ int part[SCAN_T];
    const int t = threadIdx.x;
    const int CPT = (NN + SCAN_T - 1) / SCAN_T;
    const int base = t * CPT;
    int sum = 0;
    for (int i = 0; i < CPT; ++i) {
        int idx = base + i;
        if (idx < NN) sum += counts[idx];
    }
    part[t] = sum;
    __syncthreads();
    for (int off = 1; off < SCAN_T; off <<= 1) {
        int v = (t >= off) ? part[t - off] : 0;
        __syncthreads();
        part[t] += v;
        __syncthreads();
    }
    int run = (t == 0) ? 0 : part[t - 1];
    for (int i = 0; i < CPT; ++i) {
        int idx = base + i;
        if (idx < NN) {
            offsets[idx] = run;
            cursor[idx] = run;
            run += counts[idx];
        }
    }
    if (t == SCAN_T - 1) offsets[NN] = run;
}

// ---------------------------------------------------------------------------
// k_sm: fused scatter (blocks [0, 2344)) + node MLP (blocks [2344, 2657)).
// Scatter materializes dst-sorted 64B edge records:
//   dwords: {src, dst, ev0, ev1, ev2, q0..q10}  (q = fp16-packed es*fc + {fc,0})
// MLP: gnh[idx] = (bf16(so[idx]) | bf16(nsv[idx]) << 16) -- full dword write
// (so = silu(nsb@Wm1+bm1)@Wm2+bm2).
// ---------------------------------------------------------------------------
#define SCAT_B 2344
__global__ __launch_bounds__(256) void k_sm(
    const int* __restrict__ eidx, int* __restrict__ cursor,
    const float* __restrict__ es, const float* __restrict__ enorm,
    const float* __restrict__ evec, unsigned* __restrict__ rec,
    const unsigned short* __restrict__ nsb, const float* __restrict__ nsv,
    const unsigned short* __restrict__ Wm1p, const float* __restrict__ bm1,
    const unsigned short* __restrict__ Wm2p, const float* __restrict__ bm2,
    unsigned* __restrict__ gnh) {
    __shared__ unsigned short lsh[4][16][136];
    if (blockIdx.x < SCAT_B) {
        int e = blockIdx.x * 256 + threadIdx.x;
        if (e < NE) {
            int s  = eidx[2 * e];
            int dd = eidx[2 * e + 1];
            float nrm = enorm[e];
            float fc = (nrm < CUT) ? 0.5f * (__cosf(PI_F * nrm * (1.0f / CUT)) + 1.0f) : 0.0f;
            const float* er = es + (long)e * ESZ;
            unsigned qv[11];
#pragma unroll
            for (int p = 0; p < 10; ++p)
                qv[p] = pack2h(er[2 * p] * fc, er[2 * p + 1] * fc);
            qv[10] = pack2h(fc, 0.f);
            float e0 = evec[3 * e + 0], e1 = evec[3 * e + 1], e2 = evec[3 * e + 2];
            int pos = atomicAdd(&cursor[dd], 1);
            uint4* rp = (uint4*)rec + (long)pos * 4;
            rp[0] = make_uint4((unsigned)s, (unsigned)dd,
                               __float_as_uint(e0), __float_as_uint(e1));
            rp[1] = make_uint4(__float_as_uint(e2), qv[0], qv[1], qv[2]);
            rp[2] = make_uint4(qv[3], qv[4], qv[5], qv[6]);
            rp[3] = make_uint4(qv[7], qv[8], qv[9], qv[10]);
        }
        return;
    }
    const int lane = threadIdx.x & 63;
    const int wv = threadIdx.x >> 6;
    const int wid = (blockIdx.x - SCAT_B) * 4 + wv;
    const int m0 = wid * 16;
    if (m0 >= NN) return;
    const int ml = lane & 15, q = lane >> 4;

    short8 a1[4];
#pragma unroll
    for (int kb = 0; kb < 4; ++kb)
        a1[kb] = *(const short8*)(nsb + (long)(m0 + ml) * ND + kb * 32 + q * 8);

#pragma unroll
    for (int nt = 0; nt < 8; ++nt) {
        float b = bm1[nt * 16 + ml];
        f32x4 acc = {b, b, b, b};
#pragma unroll
        for (int kb = 0; kb < 4; ++kb) {
            short8 bf = *(const short8*)(Wm1p + ((nt * 4 + kb) * 64 + lane) * 8);
            acc = __builtin_amdgcn_mfma_f32_16x16x32_bf16(a1[kb], bf, acc, 0, 0, 0);
        }
#pragma unroll
        for (int r = 0; r < 4; ++r)
            lsh[wv][q * 4 + r][nt * 16 + ml] = f2bf(silu_f(acc[r]));
    }
    __syncthreads();

    short8 a2[4];
#pragma unroll
    for (int kb = 0; kb < 4; ++kb)
        a2[kb] = *(const short8*)(&lsh[wv][ml][kb * 32 + q * 8]);

#pragma unroll
    for (int nt = 0; nt < 24; ++nt) {
        float b = bm2[nt * 16 + ml];
        f32x4 acc = {b, b, b, b};
#pragma unroll
        for (int kb = 0; kb < 4; ++kb) {
            short8 bf = *(const short8*)(Wm2p + ((nt * 4 + kb) * 64 + lane) * 8);
            acc = __builtin_amdgcn_mfma_f32_16x16x32_bf16(a2[kb], bf, acc, 0, 0, 0);
        }
#pragma unroll
        for (int r = 0; r < 4; ++r) {
            long idx = (long)(m0 + q * 4 + r) * 384 + nt * 16 + ml;
            gnh[idx] = (unsigned)f2bf(acc[r]) | ((unsigned)f2bf(nsv[idx]) << 16);
        }
    }
}

// ---------------------------------------------------------------------------
// k_edge7: chunk-unrolled segmented reduction, deep counted pipeline.
//   RUN=48 = 3 chunks x 16 edges; 600000/48 = 12500 groups exactly (no tails).
//   Same structure as the 80-edge variant; smaller RUN = 1.67x more waves,
//   raising chip-level outstanding-bytes (the measured limiter: 30% occupancy
//   x ~10 KB in flight/CU == the observed 3.2 TB/s).
//   Chunk c+3 prefetch for late c lands in next group's records / the
//   112-record zeroed pad (in-bounds; values never consumed).
// ---------------------------------------------------------------------------
#define NGRP 12500
#define RUN 48
#define CH 3

#define FLUSH() {                                                             \
    atomicAdd(&out_s[(long)cur_dst * ND + t], as);                            \
    atomicAdd(&out_v[(long)cur_dst * 384 + 0 * ND + t], av0);                 \
    atomicAdd(&out_v[(long)cur_dst * 384 + 1 * ND + t], av1);                 \
    atomicAdd(&out_v[(long)cur_dst * 384 + 2 * ND + t], av2);                 \
}

#define STEP(k, dk, gsrc) {                                                   \
    if (dk != cur_dst) {                                                      \
        if (cur_dst >= 0) FLUSH();                                            \
        cur_dst = dk;                                                         \
        as = 0.f; av0 = 0.f; av1 = 0.f; av2 = 0.f;                            \
    }                                                                         \
    const uint4 M0_ = pp[(k) & 1][0], M1_ = pp[(k) & 1][1],                   \
                M2_ = pp[(k) & 1][2], M3_ = pp[(k) & 1][3];                   \
    const unsigned XA_ = xr[(k) & 7][0], XB_ = xr[(k) & 7][1],                \
                   XC_ = xr[(k) & 7][2];                                      \
    /* refill payload with edge k+2 */                                        \
    { const unsigned* pb_ = (((k) + 2 < 16) ? bc : bn) + ((((k) + 2) & 15) << 4); \
      pp[(k) & 1][0] = *(const uint4*)(pb_);                                  \
      pp[(k) & 1][1] = *(const uint4*)(pb_ + 4);                              \
      pp[(k) & 1][2] = *(const uint4*)(pb_ + 8);                              \
      pp[(k) & 1][3] = *(const uint4*)(pb_ + 12); }                           \
    /* gather edge k+8 */                                                     \
    { const unsigned* gp_ = gnh + (long)(gsrc) * 384;                         \
      xr[(k) & 7][0] = gp_[t];                                                \
      xr[(k) & 7][1] = gp_[128 + t];                                          \
      xr[(k) & 7][2] = gp_[256 + t]; }                                        \
    unsigned ea_[11] = {M1_.y, M1_.z, M1_.w, M2_.x, M2_.y, M2_.z, M2_.w,      \
                        M3_.x, M3_.y, M3_.z, M3_.w};                          \
    float f0 = 0.f, f1 = 0.f, f2 = 0.f;                                       \
    _Pragma("unroll")                                                         \
    for (int p = 0; p < 11; ++p) {                                            \
        f0 = dot2u(ea_[p], wf[p][0], f0);                                     \
        f1 = dot2u(ea_[p], wf[p][1], f1);                                     \
        f2 = dot2u(ea_[p], wf[p][2], f2);                                     \
    }                                                                         \
    f0 *= __uint_as_float(XA_ << 16);                                         \
    f1 *= __uint_as_float(XB_ << 16);                                         \
    f2 *= __uint_as_float(XC_ << 16);                                         \
    as  += f2;                                                                \
    av0 += __uint_as_float(XA_ & 0xffff0000u) * f0 + f1 * __uint_as_float(M0_.z); \
    av1 += __uint_as_float(XB_ & 0xffff0000u) * f0 + f1 * __uint_as_float(M0_.w); \
    av2 += __uint_as_float(XC_ & 0xffff0000u) * f0 + f1 * __uint_as_float(M1_.x); \
}

#define RL(v, j) __builtin_amdgcn_readlane((int)(v), (j))

__global__ __launch_bounds__(256, 3) void k_edge7(
    const unsigned* __restrict__ rec, const unsigned* __restrict__ wfh,
    const unsigned* __restrict__ gnh,
    float* __restrict__ out_s, float* __restrict__ out_v) {
    __shared__ __align__(16) unsigned eb[4][2][256];   // per-wave dbuf chunks
    const int wv = threadIdx.x >> 6;
    const int lane = threadIdx.x & 63;
    const int grp = blockIdx.x * 2 + (wv >> 1);
    const int t = ((wv & 1) << 6) | lane;              // channel 0..127
    const long beg = (long)grp * RUN;

    hh2 wf[11][3];
#pragma unroll
    for (int p = 0; p < 11; ++p)
#pragma unroll
        for (int c = 0; c < 3; ++c)
            wf[p][c] = __builtin_bit_cast(hh2, wfh[p * 384 + c * 128 + t]);

    unsigned* const b0 = &eb[wv][0][0];
    unsigned* const b1 = &eb[wv][1][0];

    // prologue: stage chunks 0,1 into LDS (batched loads), hold chunk 2 in regs
    uint4 sA = *(const uint4*)(rec + (beg + 0)  * 16 + lane * 4);
    uint4 sB = *(const uint4*)(rec + (beg + 16) * 16 + lane * 4);
    uint4 st = *(const uint4*)(rec + (beg + 32) * 16 + lane * 4);
    *(uint4*)&b0[lane * 4] = sA;
    *(uint4*)&b1[lane * 4] = sB;
    uint2 sdC = *(const uint2*)&b0[(lane & 15) << 4];   // (src,dst) chunk 0
    uint2 sdN = *(const uint2*)&b1[(lane & 15) << 4];   // (src,dst) chunk 1

    uint4 pp[2][4];
    pp[0][0] = *(const uint4*)(b0 + 0);  pp[0][1] = *(const uint4*)(b0 + 4);
    pp[0][2] = *(const uint4*)(b0 + 8);  pp[0][3] = *(const uint4*)(b0 + 12);
    pp[1][0] = *(const uint4*)(b0 + 16); pp[1][1] = *(const uint4*)(b0 + 20);
    pp[1][2] = *(const uint4*)(b0 + 24); pp[1][3] = *(const uint4*)(b0 + 28);

    unsigned xr[8][3];
#define IG(j) { int s_ = RL(sdC.x, j);                                        \
                const unsigned* gp_ = gnh + (long)s_ * 384;                   \
                xr[j][0] = gp_[t]; xr[j][1] = gp_[128 + t];                   \
                xr[j][2] = gp_[256 + t]; }
    IG(0) IG(1) IG(2) IG(3) IG(4) IG(5) IG(6) IG(7)
#undef IG

    int cur_dst = -1;
    float as = 0.f, av0 = 0.f, av1 = 0.f, av2 = 0.f;

    for (int c = 0; c < CH; ++c) {
        unsigned* const bc = &eb[wv][c & 1][0];
        unsigned* const bn = &eb[wv][(c + 1) & 1][0];
        const int d0  = RL(sdC.y, 0),  d1  = RL(sdC.y, 1);
        const int d2  = RL(sdC.y, 2),  d3  = RL(sdC.y, 3);
        const int d4  = RL(sdC.y, 4),  d5  = RL(sdC.y, 5);
        const int d6  = RL(sdC.y, 6),  d7  = RL(sdC.y, 7);
        const int d8  = RL(sdC.y, 8),  d9  = RL(sdC.y, 9);
        const int d10 = RL(sdC.y, 10), d11 = RL(sdC.y, 11);
        const int d12 = RL(sdC.y, 12), d13 = RL(sdC.y, 13);
        const int d14 = RL(sdC.y, 14), d15 = RL(sdC.y, 15);
        const int s8  = RL(sdC.x, 8),  s9  = RL(sdC.x, 9);
        const int s10 = RL(sdC.x, 10), s11 = RL(sdC.x, 11);
        const int s12 = RL(sdC.x, 12), s13 = RL(sdC.x, 13);
        const int s14 = RL(sdC.x, 14), s15 = RL(sdC.x, 15);

        STEP(0, d0, s8)   STEP(1, d1, s9)   STEP(2, d2, s10)  STEP(3, d3, s11)
        STEP(4, d4, s12)  STEP(5, d5, s13)  STEP(6, d6, s14)  STEP(7, d7, s15)

        const int gm = (c < CH - 1) ? -1 : 0;  // last chunk: clamp gathers to node 0
        const int n0 = RL(sdN.x, 0) & gm, n1 = RL(sdN.x, 1) & gm;
        const int n2 = RL(sdN.x, 2) & gm, n3 = RL(sdN.x, 3) & gm;
        const int n4 = RL(sdN.x, 4) & gm, n5 = RL(sdN.x, 5) & gm;
        const int n6 = RL(sdN.x, 6) & gm, n7 = RL(sdN.x, 7) & gm;

        STEP(8,  d8,  n0)  STEP(9,  d9,  n1)  STEP(10, d10, n2) STEP(11, d11, n3)
        STEP(12, d12, n4)  STEP(13, d13, n5)  STEP(14, d14, n6) STEP(15, d15, n7)

        if (c < CH - 1) {
            *(uint4*)&bc[lane * 4] = st;                              // SW chunk c+2
            st = *(const uint4*)(rec + (beg + (long)(c + 3) * 16) * 16 + lane * 4);
            sdC = sdN;
            sdN = *(const uint2*)&bc[(lane & 15) << 4];               // sd chunk c+2
        }
    }
    FLUSH();
}

// ---------------------------------------------------------------------------
// k_tail: fused uvm+att. One wave owns 16 nodes end-to-end; cat and hidden
// live in wave-private LDS (no __syncthreads); ip stays in f32 regs;
// Uv stays as packed bf16 regs (same C-layout at produce and consume).
// ---------------------------------------------------------------------------
__global__ __launch_bounds__(256) void k_tail(
    const unsigned short* __restrict__ WUp, const unsigned short* __restrict__ WVp,
    const unsigned short* __restrict__ Wa1p, const float* __restrict__ ba1,
    const unsigned short* __restrict__ Wa2p, const float* __restrict__ ba2,
    float* __restrict__ out_s, float* __restrict__ out_v) {
    const int lane = threadIdx.x & 63;
    const int wv = threadIdx.x >> 6;
    const int wid = blockIdx.x * 4 + wv;
    const int m0 = wid * 16;
    if (m0 >= NN) return;
    const int ml = lane & 15, q = lane >> 4;
    __shared__ unsigned short ct[4][16][264];   // cat [s | vsq]
    __shared__ unsigned short hl[4][16][136];   // hidden

    // phase 1a: s-half of cat -> LDS (float2 load, packed bf16 dword write)
#pragma unroll
    for (int j = 0; j < 16; ++j) {
        int idx = j * 64 + lane;
        int n = idx >> 6, c2 = idx & 63;
        float2 sv = *(const float2*)(out_s + (long)(m0 + n) * 128 + c2 * 2);
        *(unsigned*)&ct[wv][n][c2 * 2] = pack2bf(sv.x, sv.y);
    }

    // phase 1b: A-frags of v
    short8 av[3][4];
#pragma unroll
    for (int ax = 0; ax < 3; ++ax)
#pragma unroll
        for (int kb = 0; kb < 4; ++kb) {
            const float* p = out_v + (long)(m0 + ml) * 384 + ax * 128 + kb * 32 + q * 8;
            float4 x = *(const float4*)p;
            float4 y = *(const float4*)(p + 4);
            short8 s;
            s[0] = (short)f2bf(x.x); s[1] = (short)f2bf(x.y);
            s[2] = (short)f2bf(x.z); s[3] = (short)f2bf(x.w);
            s[4] = (short)f2bf(y.x); s[5] = (short)f2bf(y.y);
            s[6] = (short)f2bf(y.z); s[7] = (short)f2bf(y.w);
            av[ax][kb] = s;
        }

    // phase 1c: Uv/Vv MFMA; vsq -> LDS, ip -> regs, Uv -> packed bf16 regs
    f32x4 ipr[8];
    unsigned upk[8][3][2];
#pragma unroll
    for (int nt = 0; nt < 8; ++nt) {
        f32x4 u0 = {0.f,0.f,0.f,0.f}, u1 = u0, u2 = u0;
        f32x4 v0 = u0, v1 = u0, v2 = u0;
#pragma unroll
        for (int kb = 0; kb < 4; ++kb) {
            short8 bu = *(const short8*)(WUp + ((nt * 4 + kb) * 64 + lane) * 8);
            short8 bv = *(const short8*)(WVp + ((nt * 4 + kb) * 64 + lane) * 8);
            u0 = __builtin_amdgcn_mfma_f32_16x16x32_bf16(av[0][kb], bu, u0, 0, 0, 0);
            u1 = __builtin_amdgcn_mfma_f32_16x16x32_bf16(av[1][kb], bu, u1, 0, 0, 0);
            u2 = __builtin_amdgcn_mfma_f32_16x16x32_bf16(av[2][kb], bu, u2, 0, 0, 0);
            v0 = __builtin_amdgcn_mfma_f32_16x16x32_bf16(av[0][kb], bv, v0, 0, 0, 0);
            v1 = __builtin_amdgcn_mfma_f32_16x16x32_bf16(av[1][kb], bv, v1, 0, 0, 0);
            v2 = __builtin_amdgcn_mfma_f32_16x16x32_bf16(av[2][kb], bv, v2, 0, 0, 0);
        }
        const int c = nt * 16 + ml;
#pragma unroll
        for (int r = 0; r < 4; ++r) {
            float vs  = v0[r] * v0[r] + v1[r] * v1[r] + v2[r] * v2[r];
            ct[wv][q * 4 + r][128 + c] = f2bf(vs);
            ipr[nt][r] = u0[r] * v0[r] + u1[r] * v1[r] + u2[r] * v2[r];
        }
        upk[nt][0][0] = pack2bf(u0[0], u0[1]); upk[nt][0][1] = pack2bf(u0[2], u0[3]);
        upk[nt][1][0] = pack2bf(u1[0], u1[1]); upk[nt][1][1] = pack2bf(u1[2], u1[3]);
        upk[nt][2][0] = pack2bf(u2[0], u2[1]); upk[nt][2][1] = pack2bf(u2[2], u2[3]);
    }

    // phase 2a: a1 frags from cat (wave-private LDS, in-order DS => no barrier)
    short8 a1[8];
#pragma unroll
    for (int kb = 0; kb < 8; ++kb)
        a1[kb] = *(const short8*)(&ct[wv][ml][kb * 32 + q * 8]);

#pragma unroll
    for (int nt = 0; nt < 8; ++nt) {
        float b = ba1[nt * 16 + ml];
        f32x4 acc = {b, b, b, b};
#pragma unroll
        for (int kb = 0; kb < 8; ++kb) {
            short8 bf = *(const short8*)(Wa1p + ((nt * 8 + kb) * 64 + lane) * 8);
            acc = __builtin_amdgcn_mfma_f32_16x16x32_bf16(a1[kb], bf, acc, 0, 0, 0);
        }
#pragma unroll
        for (int r = 0; r < 4; ++r)
            hl[wv][q * 4 + r][nt * 16 + ml] = f2bf(silu_f(acc[r]));
    }

    short8 h[4];
#pragma unroll
    for (int kb = 0; kb < 4; ++kb)
        h[kb] = *(const short8*)(&hl[wv][ml][kb * 32 + q * 8]);

#pragma unroll
    for (int nt = 0; nt < 8; ++nt) {
        float b0 = ba2[nt * 16 + ml];
        float b1 = ba2[128 + nt * 16 + ml];
        f32x4 aS = {b0, b0, b0, b0};
        f32x4 aG = {b1, b1, b1, b1};
#pragma unroll
        for (int kb = 0; kb < 4; ++kb) {
            short8 bS = *(const short8*)(Wa2p + (((nt) * 4 + kb) * 64 + lane) * 8);
            short8 bG = *(const short8*)(Wa2p + (((nt + 8) * 4 + kb) * 64 + lane) * 8);
            aS = __builtin_amdgcn_mfma_f32_16x16x32_bf16(h[kb], bS, aS, 0, 0, 0);
            aG = __builtin_amdgcn_mfma_f32_16x16x32_bf16(h[kb], bG, aG, 0, 0, 0);
        }
#pragma unroll
        for (int r = 0; r < 4; ++r) {
            long grow = m0 + q * 4 + r;
            long o = grow * 128 + nt * 16 + ml;
            out_s[o] = out_s[o] + aS[r] + aG[r] * ipr[nt][r];
        }
    }

#pragma unroll
    for (int nt = 0; nt < 8; ++nt) {
        float b2 = ba2[256 + nt * 16 + ml];
        f32x4 aV = {b2, b2, b2, b2};
#pragma unroll
        for (int kb = 0; kb < 4; ++kb) {
            short8 bV = *(const short8*)(Wa2p + (((nt + 16) * 4 + kb) * 64 + lane) * 8);
            aV = __builtin_amdgcn_mfma_f32_16x16x32_bf16(h[kb], bV, aV, 0, 0, 0);
        }
#pragma unroll
        for (int r = 0; r < 4; ++r) {
            long grow = m0 + q * 4 + r;
            int c = nt * 16 + ml;
#pragma unroll
            for (int ax = 0; ax < 3; ++ax) {
                unsigned pk = upk[nt][ax][r >> 1];
                unsigned short uh = (r & 1) ? (unsigned short)(pk >> 16)
                                            : (unsigned short)(pk & 0xffffu);
                long o = grow * 384 + ax * 128 + c;
                out_v[o] = out_v[o] + aV[r] * bf2f(uh);
            }
        }
    }
}

// ---------------------------------------------------------------------------
extern "C" void kernel_launch(void* const* d_in, const int* in_sizes, int n_in,
                              void* d_out, int out_size, void* d_ws, size_t ws_size,
                              hipStream_t stream) {
    const float* ns    = (const float*)d_in[0];
    const float* nsv   = (const float*)d_in[1];
    const float* es    = (const float*)d_in[2];
    const float* evec  = (const float*)d_in[3];
    const float* enorm = (const float*)d_in[4];
    const int*   eidx  = (const int*)d_in[5];
    const float* Wf    = (const float*)d_in[6];
    const float* bfb   = (const float*)d_in[7];
    const float* Wm1   = (const float*)d_in[8];
    const float* bm1   = (const float*)d_in[9];
    const float* Wm2   = (const float*)d_in[10];
    const float* bm2   = (const float*)d_in[11];
    const float* WU    = (const float*)d_in[12];
    const float* WV    = (const float*)d_in[13];
    const float* Wa1   = (const float*)d_in[14];
    const float* ba1   = (const float*)d_in[15];
    const float* Wa2   = (const float*)d_in[16];
    const float* ba2   = (const float*)d_in[17];

    float* out_s = (float*)d_out;
    float* out_v = out_s + (size_t)NN * ND;

    // ---- workspace layout ----
    char* w = (char*)d_ws;
    unsigned short* p1  = (unsigned short*)(w + 0);        //  32,768 B
    unsigned short* p2  = (unsigned short*)(w + 32768);    //  98,304 B
    unsigned short* pU  = (unsigned short*)(w + 131072);   //  32,768 B
    unsigned short* pV  = (unsigned short*)(w + 163840);   //  32,768 B
    unsigned short* pa1 = (unsigned short*)(w + 196608);   //  65,536 B
    unsigned short* pa2 = (unsigned short*)(w + 262144);   //  98,304 B
    unsigned* wfh = (unsigned*)(w + 360448);               //  16,896 B
    int* counts = (int*)(w + 377344);                      //  80,000 B
    int* offs   = (int*)(w + 457344);                      //  80,004 B
    int* cursor = (int*)(w + 537408);                      //  80,000 B
    // dst-sorted 64B edge records; padded to 600,112 edges for chunk prefetch
    unsigned* rec = (unsigned*)(w + 617408);               // 38,407,168 B
    char* u0 = w + 39024576;
    unsigned* gnh       = (unsigned*)(u0);                     // 30,720,000 B
    unsigned short* nsb = (unsigned short*)(u0 + 30720000);    //  5,120,000 B

    hipMemsetAsync(counts, 0, (size_t)NN * sizeof(int), stream);
    hipMemsetAsync(rec + (size_t)NE * 16, 0, 112 * 64, stream);  // zero pad records
    k_front<<<(int)((R3 + 255) / 256), 256, 0, stream>>>(
        (const float4*)ns, (const float4*)nsv, eidx, Wf, bfb,
        Wm1, Wm2, WU, WV, Wa1, Wa2,
        (float4*)out_s, (float4*)out_v, (ushort4*)nsb,
        p1, p2, pU, pV, pa1, pa2, wfh, counts);
    k_scan<<<1, SCAN_T, 0, stream>>>(counts, offs, cursor);
    k_sm<<<SCAT_B + 313, 256, 0, stream>>>(eidx, cursor, es, enorm, evec, rec,
                                           nsb, nsv, p1, bm1, p2, bm2, gnh);
    k_edge7<<<NGRP / 2, 256, 0, stream>>>(rec, wfh, gnh, out_s, out_v);
    k_tail<<<313, 256, 0, stream>>>(pU, pV, pa1, ba1, pa2, ba2, out_s, out_v);
}